// Round 8
// baseline (16.411 us; speedup 1.0000x reference)
//
#include <hip/hip_runtime.h>

#define NN   50000
#define NE   800000
#define CH   64
#define NREL 8
#define NWRD ((NN + 63) / 64)   // 782 bitmap words

#define NGID   (NN * 16)        // 800000 node-quarter work items
#define D1BLK  784
#define D1THR  (D1BLK * 256)    // 200704 threads, 4 gids each

typedef float f32x4 __attribute__((ext_vector_type(4)));
typedef int   i32x4 __attribute__((ext_vector_type(4)));

// Dispatch 1: 784 blocks x 256, 4-deep unrolled grid-stride (4x MLP/thread).
//  Phase a (16 threads/node, float4): splice history row (~99.995% of nodes)
//  or out = x @ loop_w + bias for the ~2.5 uncached nodes.
//  Phase b (first 782 waves): ballot "hmap[node] < 0" -> 6.25 KB rare-node
//  bitmap in d_ws. Every word written every call -> deterministic.
__global__ __launch_bounds__(256)
void splice_and_flag(const float* __restrict__ x,
                     const float* __restrict__ loop_w,
                     const float* __restrict__ bias,
                     const float* __restrict__ hist,
                     const int* __restrict__ hmap,
                     float* __restrict__ out,
                     unsigned long long* __restrict__ bitmap) {
    int gtid = blockIdx.x * blockDim.x + threadIdx.x;   // [0, 200704)
    f32x4* out4 = (f32x4*)out;

#pragma unroll 4
    for (int it = 0; it < 4; ++it) {
        int gid = gtid + it * D1THR;
        if (gid >= NGID) break;
        int n = gid >> 4;
        int q = gid & 15;
        int hm = hmap[n];
        if (hm >= 0) {
            out4[n * 16 + q] = ((const f32x4*)hist)[hm * 16 + q];
        } else {
            int c0 = q * 4;
            f32x4 acc = ((const f32x4*)bias)[q];
            const float* xr = x + n * CH;
#pragma unroll 8
            for (int i = 0; i < CH; ++i) {
                float xv = xr[i];
                f32x4 w = *(const f32x4*)(loop_w + i * CH + c0);
                acc += xv * w;
            }
            out4[n * 16 + q] = acc;
        }
    }

    // ---- phase b: rare-node bitmap ----
    int wid = gtid >> 6;
    if (wid < NWRD) {
        int lane = threadIdx.x & 63;
        int node = (wid << 6) + lane;
        int h = (node < NN) ? hmap[node] : 0;
        unsigned long long m = __ballot(h < 0);
        if (lane == 0) bitmap[wid] = m;
    }
}

// Dispatch 2: 782 blocks x 256. Each thread: one int4 of dst (4 edges),
// 4 probes of the L1-resident 6.25 KB bitmap. Qualifying edges (~40
// grid-wide): whole wave computes the 64-channel message (lane = channel),
// atomicAdd into out[dst].
__global__ __launch_bounds__(256)
void scan_apply(const float* __restrict__ x,
                const float* __restrict__ W,
                const int* __restrict__ src,
                const int* __restrict__ dst,
                const int* __restrict__ et,
                const unsigned long long* __restrict__ bitmap,
                float* __restrict__ out) {
    int gtid = blockIdx.x * blockDim.x + threadIdx.x;   // int4 index
    if (gtid >= NE / 4) return;
    int lane = threadIdx.x & 63;
    int wbase = gtid - lane;                 // wave's first int4 index

    i32x4 d4 = ((const i32x4*)dst)[gtid];

#pragma unroll 4
    for (int k = 0; k < 4; ++k) {
        int d = d4[k];
        unsigned long long w = bitmap[d >> 6];
        bool need = (w >> (d & 63)) & 1ULL;
        unsigned long long mask = __ballot(need);
        while (mask) {
            int l = __ffsll((long long)mask) - 1;
            mask &= mask - 1;
            int e = ((wbase + l) << 2) + k;
            int dd = __shfl(d, l);
            int s  = src[e];
            int r  = et[e];
            const float* xr = x + s * CH;
            const float* wr = W + r * CH * CH + lane;
            float acc = 0.0f;
#pragma unroll 8
            for (int i = 0; i < CH; ++i)
                acc += xr[i] * wr[i * CH];
            atomicAdd(out + dd * CH + lane, acc);
        }
    }
}

// Fallback if ws is too small (won't trigger): direct hmap probe.
__global__ void edge_fused_fb(const float* __restrict__ x,
                              const float* __restrict__ W,
                              const int* __restrict__ src,
                              const int* __restrict__ dst,
                              const int* __restrict__ et,
                              const int* __restrict__ hmap,
                              float* __restrict__ out) {
    int gtid = blockIdx.x * blockDim.x + threadIdx.x;
    int lane = threadIdx.x & 63;
    int e0 = gtid - lane;
    if (e0 >= NE) return;
    int d = dst[e0 + lane];
    unsigned long long mask = __ballot(hmap[d] < 0);
    while (mask) {
        int l = __ffsll((long long)mask) - 1;
        mask &= mask - 1;
        int e = e0 + l;
        int dd = __shfl(d, l);
        int s  = src[e];
        int r  = et[e];
        const float* xr = x + s * CH;
        const float* wr = W + r * CH * CH + lane;
        float acc = 0.0f;
#pragma unroll 8
        for (int i = 0; i < CH; ++i)
            acc += xr[i] * wr[i * CH];
        atomicAdd(out + dd * CH + lane, acc);
    }
}

extern "C" void kernel_launch(void* const* d_in, const int* in_sizes, int n_in,
                              void* d_out, int out_size, void* d_ws, size_t ws_size,
                              hipStream_t stream) {
    const float* x      = (const float*)d_in[0];
    const float* W      = (const float*)d_in[1];
    const float* loop_w = (const float*)d_in[2];
    const float* bias   = (const float*)d_in[3];
    const float* hist   = (const float*)d_in[4];
    const int*   src    = (const int*)d_in[5];
    const int*   dst    = (const int*)d_in[6];
    const int*   et     = (const int*)d_in[7];
    const int*   hmap   = (const int*)d_in[8];
    float* out = (float*)d_out;

    if (ws_size >= (size_t)NWRD * 8) {
        unsigned long long* bitmap = (unsigned long long*)d_ws;
        splice_and_flag<<<D1BLK, 256, 0, stream>>>(
            x, loop_w, bias, hist, hmap, out, bitmap);
        scan_apply<<<(NE / 4 + 255) / 256, 256, 0, stream>>>(
            x, W, src, dst, et, bitmap, out);
    } else {
        edge_fused_fb<<<(NE + 255) / 256, 256, 0, stream>>>(  // degenerate path
            x, W, src, dst, et, hmap, out);
    }
}

// Round 9
// 14.592 us; speedup vs baseline: 1.1247x; 1.1247x over previous
//
#include <hip/hip_runtime.h>

#define NN   50000
#define NE   800000
#define CH   64
#define NREL 8
#define NWRD ((NN + 63) / 64)   // 782 bitmap words

// Dispatch 1: 3125 blocks x 256.
//  Phase a (16 threads/node, float4): splice history row (~99.995% of nodes)
//  or out = x @ loop_w + bias for the ~2.5 uncached nodes.
//  Phase b (first 782 waves): ballot "hmap[node] < 0" over 64 nodes/wave,
//  lane 0 writes the 64-bit word -> 6.25 KB rare-node bitmap in d_ws.
//  Every word written every call -> deterministic, no init dispatch.
__global__ __launch_bounds__(256)
void splice_and_flag(const float* __restrict__ x,
                     const float* __restrict__ loop_w,
                     const float* __restrict__ bias,
                     const float* __restrict__ hist,
                     const int* __restrict__ hmap,
                     float* __restrict__ out,
                     unsigned long long* __restrict__ bitmap) {
    int gtid = blockIdx.x * blockDim.x + threadIdx.x;   // [0, 800000)

    // ---- phase a: node splice / self-loop ----
    int n = gtid >> 4;
    int q = gtid & 15;
    int hm = hmap[n];
    float4* out4 = (float4*)out;
    if (hm >= 0) {
        out4[n * 16 + q] = ((const float4*)hist)[hm * 16 + q];
    } else {
        int c0 = q * 4;
        float4 acc = ((const float4*)bias)[q];
        const float* xr = x + n * CH;
#pragma unroll 8
        for (int i = 0; i < CH; ++i) {
            float xv = xr[i];
            float4 w = *(const float4*)(loop_w + i * CH + c0);
            acc.x += xv * w.x;
            acc.y += xv * w.y;
            acc.z += xv * w.z;
            acc.w += xv * w.w;
        }
        out4[n * 16 + q] = acc;
    }

    // ---- phase b: rare-node bitmap ----
    int wid = gtid >> 6;
    if (wid < NWRD) {
        int lane = threadIdx.x & 63;
        int node = (wid << 6) + lane;
        int h = (node < NN) ? hmap[node] : 0;
        unsigned long long m = __ballot(h < 0);
        if (lane == 0) bitmap[wid] = m;
    }
}

// Dispatch 2: 3125 blocks x 256. Per edge: coalesced dst load + L1-resident
// bitmap probe (6.25 KB). Qualifying edges (~40 grid-wide): whole wave
// computes the 64-channel message (lane = channel), atomicAdd into out[dst].
__global__ __launch_bounds__(256)
void scan_apply(const float* __restrict__ x,
                const float* __restrict__ W,
                const int* __restrict__ src,
                const int* __restrict__ dst,
                const int* __restrict__ et,
                const unsigned long long* __restrict__ bitmap,
                float* __restrict__ out) {
    int gtid = blockIdx.x * blockDim.x + threadIdx.x;   // [0, 800000)
    int lane = threadIdx.x & 63;
    int e0 = gtid - lane;
    int d = dst[gtid];
    unsigned long long w = bitmap[d >> 6];
    bool need = (w >> (d & 63)) & 1ULL;
    unsigned long long mask = __ballot(need);
    while (mask) {
        int l = __ffsll((long long)mask) - 1;
        mask &= mask - 1;
        int e = e0 + l;
        int dd = __shfl(d, l);
        int s  = src[e];
        int r  = et[e];
        const float* xr = x + s * CH;
        const float* wr = W + r * CH * CH + lane;
        float acc = 0.0f;
#pragma unroll 8
        for (int i = 0; i < CH; ++i)
            acc += xr[i] * wr[i * CH];
        atomicAdd(out + dd * CH + lane, acc);
    }
}

// Fallback if ws is too small (won't trigger with the 268 MB ws): R2 scheme.
__global__ void edge_fused_fb(const float* __restrict__ x,
                              const float* __restrict__ W,
                              const int* __restrict__ src,
                              const int* __restrict__ dst,
                              const int* __restrict__ et,
                              const int* __restrict__ hmap,
                              float* __restrict__ out) {
    int gtid = blockIdx.x * blockDim.x + threadIdx.x;
    int lane = threadIdx.x & 63;
    int e0 = gtid - lane;
    if (e0 >= NE) return;
    int d = dst[e0 + lane];
    unsigned long long mask = __ballot(hmap[d] < 0);
    while (mask) {
        int l = __ffsll((long long)mask) - 1;
        mask &= mask - 1;
        int e = e0 + l;
        int dd = __shfl(d, l);
        int s  = src[e];
        int r  = et[e];
        const float* xr = x + s * CH;
        const float* wr = W + r * CH * CH + lane;
        float acc = 0.0f;
#pragma unroll 8
        for (int i = 0; i < CH; ++i)
            acc += xr[i] * wr[i * CH];
        atomicAdd(out + dd * CH + lane, acc);
    }
}

extern "C" void kernel_launch(void* const* d_in, const int* in_sizes, int n_in,
                              void* d_out, int out_size, void* d_ws, size_t ws_size,
                              hipStream_t stream) {
    const float* x      = (const float*)d_in[0];
    const float* W      = (const float*)d_in[1];
    const float* loop_w = (const float*)d_in[2];
    const float* bias   = (const float*)d_in[3];
    const float* hist   = (const float*)d_in[4];
    const int*   src    = (const int*)d_in[5];
    const int*   dst    = (const int*)d_in[6];
    const int*   et     = (const int*)d_in[7];
    const int*   hmap   = (const int*)d_in[8];
    float* out = (float*)d_out;

    if (ws_size >= (size_t)NWRD * 8) {
        unsigned long long* bitmap = (unsigned long long*)d_ws;
        splice_and_flag<<<NN * 16 / 256, 256, 0, stream>>>(
            x, loop_w, bias, hist, hmap, out, bitmap);
        scan_apply<<<NE / 256, 256, 0, stream>>>(
            x, W, src, dst, et, bitmap, out);
    } else {
        splice_and_flag<<<NN * 16 / 256, 256, 0, stream>>>(
            x, loop_w, bias, hist, hmap, out, (unsigned long long*)d_out);
        edge_fused_fb<<<(NE + 255) / 256, 256, 0, stream>>>(
            x, W, src, dst, et, hmap, out);
    }
}